// Round 19
// baseline (31.546 us; speedup 1.0000x reference)
//
#include <hip/hip_runtime.h>
#include <stdint.h>

// Blocksparse Deep ReLU GAM forward via chained f16 MFMA.
// 128 towers, each 2->16->12->8->1 MLP over input pair (2t, 2t+1);
// out[s] = sum_t tower_t(x[s]) + bias. shape_loss output = zeros(128).
//
// v_mfma_f32_16x16x16_f16 D layout (row=(lane>>4)*4+reg, col=lane&15)
// equals the B layout (k=(lane>>4)*4+i, col=lane&15), so Y = W·X chains
// layer-to-layer with only lane-local relu + f32->f16 cvt.
//
// Round 19: L3 on the VALU. The 4th MFMA per chain computed a 1x8 dot
// (25% of MFMA issue, ~40cy of chain latency) for one scalar row. But
// d2's D-layout already has h2 lane-local: lane (kg,col) holds rows
// 4kg..4kg+3 for sample col (rows 8-15 structurally zero). With
// w3[4kg..4kg+3] packed per-kg next to b1/b2, L3 = 4 lane-local f32
// FMAs; the cross-kg combine is two __shfl_down at the very end.
// MFMAs/wave 256->192; chain latency -20%; L3 in f32 (better accuracy).
// Kept: r18 quad_chain 4-way lockstep ILP, same-g blocks (L1 weights),
// rolled pack loop (liveness fence), launch_bounds(256,4), named
// scalars only (rule #20), b1/b2 as C operands, parallel b3 reduce,
// out-zeroing in pack_frags.
//
// 4-tower shared B0: lane (kg,col) carries B0 rows 4kg..4kg+2 =
// {x[s][2(tb+kg)], x[s][2(tb+kg)+1], 1}; tower tb+j's A0 is nonzero only
// in k-columns 4j..4j+2, so one coalesced all-lane x load feeds 4 towers.
//
// Bias: b0 -> A0 k=4j+2 (homogeneous coord); b1 -> C of L1 MFMA;
// b2 -> C of L2 MFMA; sum_t b3[t] + bias -> one scalar at the end.

constexpr int BATCH = 32768;
constexpr int FEAT  = 256;
constexpr int NTOW  = 128;
constexpr int OUTN  = BATCH + NTOW;   // out + shape_loss

constexpr int REC = 560;  // dwords per tower record (2240 B, 16B-aligned)
// [0,512) = 64 lanes x 8 dwords {a0.lo,a0.hi,a1.lo,a1.hi,a2.lo,a2.hi,
// a3.lo,a3.hi (a3 unused)}; [512,560) = per kg (12 dwords, 16B-aligned
// groups): {b1[4kg..4kg+3], b2[4kg..4kg+3], w3[4kg..4kg+3]}.
constexpr int OFF_BB = 512;

typedef _Float16 h4_t __attribute__((ext_vector_type(4)));
typedef __fp16   hp2_t __attribute__((ext_vector_type(2)));
typedef float    f4_t __attribute__((ext_vector_type(4)));

static __device__ __forceinline__ h4_t u2_to_h4(uint32_t lo, uint32_t hi) {
  union { uint2 u; h4_t h; } cv; cv.u.x = lo; cv.u.y = hi; return cv.h;
}
static __device__ __forceinline__ void h4_to_u2(h4_t v, uint32_t* d) {
  union { h4_t h; uint2 u; } cv; cv.h = v; d[0] = cv.u.x; d[1] = cv.u.y;
}
// pack 4 f32 -> 4 f16 (2x v_cvt_pkrtz) then packed relu (v_pk_max_f16 x2).
// relu(cvt(x)) == cvt(relu(x)): RTZ preserves sign; -0 is harmless in dots.
static __device__ __forceinline__ h4_t relu_pack4(const f4_t d) {
  const hp2_t lo = __builtin_amdgcn_cvt_pkrtz(d[0], d[1]);
  const hp2_t hi = __builtin_amdgcn_cvt_pkrtz(d[2], d[3]);
  h4_t r;
  r[0] = (_Float16)lo[0]; r[1] = (_Float16)lo[1];
  r[2] = (_Float16)hi[0]; r[3] = (_Float16)hi[1];
  const h4_t z = {(_Float16)0.f, (_Float16)0.f, (_Float16)0.f, (_Float16)0.f};
  return __builtin_elementwise_max(r, z);
}
// Build a B0 fragment from an x pair: {x0, x1, 1, 0}.
static __device__ __forceinline__ h4_t make_b0(const float* __restrict__ p) {
  const float2 xv = *(const float2*)p;
  const hp2_t xh = __builtin_amdgcn_cvt_pkrtz(xv.x, xv.y);
  h4_t b;
  b[0] = (_Float16)xh[0]; b[1] = (_Float16)xh[1];
  b[2] = (_Float16)1.0f;  b[3] = (_Float16)0.0f;
  return b;
}
// L3 for one tower on the VALU: lane-local dot of w3 rows 4kg..4kg+3
// with relu(d2) (same rows). Lanes kg>=2 have w3 frag = 0.
static __device__ __forceinline__ float dot_l3(const f4_t w3, const f4_t d2) {
  float p = w3[0] * fmaxf(d2[0], 0.f);
  p = fmaf(w3[1], fmaxf(d2[1], 0.f), p);
  p = fmaf(w3[2], fmaxf(d2[2], 0.f), p);
  p = fmaf(w3[3], fmaxf(d2[3], 0.f), p);
  return p;
}

#define MFMA16(A, B, C) __builtin_amdgcn_mfma_f32_16x16x16f16((A), (B), (C), 0, 0, 0)

// Four towers' chains for one 16-sample tile, layers in lockstep:
// each layer step = 4 independent MFMAs (or 4 VALU dots for L3) -> 4-way
// ILP covers the MFMA->relu->MFMA dependency latency. All values named.
static __device__ __forceinline__ float quad_chain(
    h4_t a0_0, h4_t a1_0, h4_t a2_0, f4_t c1_0, f4_t c2_0, f4_t w3_0,
    h4_t a0_1, h4_t a1_1, h4_t a2_1, f4_t c1_1, f4_t c2_1, f4_t w3_1,
    h4_t a0_2, h4_t a1_2, h4_t a2_2, f4_t c1_2, f4_t c2_2, f4_t w3_2,
    h4_t a0_3, h4_t a1_3, h4_t a2_3, f4_t c1_3, f4_t c2_3, f4_t w3_3,
    h4_t b0) {
  const f4_t zc = {0.f, 0.f, 0.f, 0.f};
  const f4_t d0_0 = MFMA16(a0_0, b0, zc);
  const f4_t d0_1 = MFMA16(a0_1, b0, zc);
  const f4_t d0_2 = MFMA16(a0_2, b0, zc);
  const f4_t d0_3 = MFMA16(a0_3, b0, zc);
  const h4_t h0_0 = relu_pack4(d0_0);
  const h4_t h0_1 = relu_pack4(d0_1);
  const h4_t h0_2 = relu_pack4(d0_2);
  const h4_t h0_3 = relu_pack4(d0_3);
  const f4_t d1_0 = MFMA16(a1_0, h0_0, c1_0);
  const f4_t d1_1 = MFMA16(a1_1, h0_1, c1_1);
  const f4_t d1_2 = MFMA16(a1_2, h0_2, c1_2);
  const f4_t d1_3 = MFMA16(a1_3, h0_3, c1_3);
  const h4_t h1_0 = relu_pack4(d1_0);
  const h4_t h1_1 = relu_pack4(d1_1);
  const h4_t h1_2 = relu_pack4(d1_2);
  const h4_t h1_3 = relu_pack4(d1_3);
  const f4_t d2_0 = MFMA16(a2_0, h1_0, c2_0);
  const f4_t d2_1 = MFMA16(a2_1, h1_1, c2_1);
  const f4_t d2_2 = MFMA16(a2_2, h1_2, c2_2);
  const f4_t d2_3 = MFMA16(a2_3, h1_3, c2_3);
  // L3 on VALU: lane-local partial dots (rows 4kg..4kg+3).
  const float p0 = dot_l3(w3_0, d2_0);
  const float p1 = dot_l3(w3_1, d2_1);
  const float p2 = dot_l3(w3_2, d2_2);
  const float p3 = dot_l3(w3_3, d2_3);
  return (p0 + p1) + (p2 + p3);
}

__global__ void pack_frags(
    const float* __restrict__ W0, const float* __restrict__ B0,
    const float* __restrict__ W1, const float* __restrict__ B1,
    const float* __restrict__ W2, const float* __restrict__ B2,
    const float* __restrict__ W3, const float* __restrict__ B3,
    const float* __restrict__ bias, uint32_t* __restrict__ pack,
    float* __restrict__ out) {
  const int t   = blockIdx.x;
  const int l   = threadIdx.x;      // 64 threads = 64 lanes
  const int row = l & 15;           // A-frag row  = lane&15
  const int kg  = l >> 4;           // A-frag k    = (lane>>4)*4 + r
  uint32_t* rec = pack + t * REC;

  // Zero the output buffer (out[0:BATCH] accumulated by atomics;
  // shape_loss[BATCH:BATCH+NTOW] stays 0). Grid-stride over all blocks.
  for (int i = t * 64 + l; i < OUTN; i += NTOW * 64) out[i] = 0.f;

  h4_t a0, a1, a2;
#pragma unroll
  for (int r = 0; r < 4; ++r) {
    const int k = kg * 4 + r;
    // A0: tower t occupies k-columns 4*(t&3) .. 4*(t&3)+2.
    float v0 = 0.f;
    if (kg == (t & 3)) {
      if (r < 2)       v0 = W0[(16*t + row) * FEAT + 2*t + r];
      else if (r == 2) v0 = B0[16*t + row];
    }
    a0[r] = (_Float16)v0;

    float v1 = 0.f;
    if (row < 12)    v1 = W1[(12*t + row) * (16*NTOW) + 16*t + k];
    a1[r] = (_Float16)v1;

    float v2 = 0.f;
    if (row < 8 && k < 12) v2 = W2[(8*t + row) * (12*NTOW) + 12*t + k];
    a2[r] = (_Float16)v2;
  }
  uint32_t* lrec = rec + 8 * l;
  h4_to_u2(a0, lrec + 0);
  h4_to_u2(a1, lrec + 2);
  h4_to_u2(a2, lrec + 4);
  lrec[6] = 0u; lrec[7] = 0u;   // a3 slot unused

  if (l < 16) {
    // Per-kg 12-dword group: {b1[4kg..4kg+3], b2[...], w3[...]}.
    const float b1v = (l < 12) ? B1[12*t + l] : 0.f;
    const float b2v = (l < 8) ? B2[8*t + l] : 0.f;
    const float w3v = (l < 8) ? W3[t * (8*NTOW) + 8*t + l] : 0.f;
    const int base = OFF_BB + (l >> 2) * 12;
    rec[base +     (l & 3)] = __float_as_uint(b1v);
    rec[base + 4 + (l & 3)] = __float_as_uint(b2v);
    rec[base + 8 + (l & 3)] = __float_as_uint(w3v);
  }
  if (t == 0) {
    // Parallel b3+bias sum: 64 lanes load 2 each, wave shuffle-reduce.
    float s = B3[l] + B3[64 + l];
#pragma unroll
    for (int m = 32; m >= 1; m >>= 1) s += __shfl_xor(s, m);
    if (l == 0) pack[NTOW * REC] = __float_as_uint(s + bias[0]);
  }
}

// One block: tower group g (16 towers) x 256 samples (4 waves x 64).
// All 4 waves stream the SAME 16 tower records -> L1-resident weights.
__global__ __launch_bounds__(256, 4) void bs_mfma(
    const float* __restrict__ x, const uint32_t* __restrict__ pack,
    float* __restrict__ out) {
  const int warp  = threadIdx.x >> 6;
  const int lane  = threadIdx.x & 63;
  const int col   = lane & 15;       // sample within tile
  const int kg    = lane >> 4;
  const int g     = blockIdx.x & 7;  // tower group: towers [16g, 16g+16)
  const int tile  = blockIdx.x >> 3;
  const int sbase = tile * 256 + warp * 64;

  const float cbias = __uint_as_float(pack[NTOW * REC]);

  // Per-lane x base: sample row (sbase+col), feature 2*(16g + kg).
  const float* __restrict__ xb =
      x + (size_t)(sbase + col) * FEAT + 2 * (g * 16 + kg);

  const uint32_t* __restrict__ fp = pack + (size_t)(g * 16) * REC + 8 * lane;
  const uint32_t* __restrict__ bp = pack + (size_t)(g * 16) * REC + OFF_BB + kg * 12;

  float acc0 = 0.f, acc1 = 0.f, acc2 = 0.f, acc3 = 0.f;

#pragma unroll 1
  for (int p = 0; p < 4; ++p) {      // packs of 4 towers — ROLLED
    // B0 fragments for this pack's 4 sample tiles (shared by the pack's
    // 4 towers). Named scalars -> guaranteed register allocation.
    const float* __restrict__ xp = xb + 8 * p;
    const h4_t bq0 = make_b0(xp + (size_t)0 * 16 * FEAT);
    const h4_t bq1 = make_b0(xp + (size_t)1 * 16 * FEAT);
    const h4_t bq2 = make_b0(xp + (size_t)2 * 16 * FEAT);
    const h4_t bq3 = make_b0(xp + (size_t)3 * 16 * FEAT);

    // Load all 4 towers' fragments (named; weight state in registers).
    const uint32_t* __restrict__ fpp = fp + (size_t)(4 * p) * REC;
    const uint32_t* __restrict__ bpp = bp + (size_t)(4 * p) * REC;
    const uint4  w01_0 = *(const uint4*)(fpp + 0 * REC);
    const uint2  w2_0  = *(const uint2*)(fpp + 0 * REC + 4);
    const uint4  w01_1 = *(const uint4*)(fpp + 1 * REC);
    const uint2  w2_1  = *(const uint2*)(fpp + 1 * REC + 4);
    const uint4  w01_2 = *(const uint4*)(fpp + 2 * REC);
    const uint2  w2_2  = *(const uint2*)(fpp + 2 * REC + 4);
    const uint4  w01_3 = *(const uint4*)(fpp + 3 * REC);
    const uint2  w2_3  = *(const uint2*)(fpp + 3 * REC + 4);
    const float4 bbA_0 = *(const float4*)(bpp + 0 * REC);
    const float4 bbB_0 = *(const float4*)(bpp + 0 * REC + 4);
    const float4 bbW_0 = *(const float4*)(bpp + 0 * REC + 8);
    const float4 bbA_1 = *(const float4*)(bpp + 1 * REC);
    const float4 bbB_1 = *(const float4*)(bpp + 1 * REC + 4);
    const float4 bbW_1 = *(const float4*)(bpp + 1 * REC + 8);
    const float4 bbA_2 = *(const float4*)(bpp + 2 * REC);
    const float4 bbB_2 = *(const float4*)(bpp + 2 * REC + 4);
    const float4 bbW_2 = *(const float4*)(bpp + 2 * REC + 8);
    const float4 bbA_3 = *(const float4*)(bpp + 3 * REC);
    const float4 bbB_3 = *(const float4*)(bpp + 3 * REC + 4);
    const float4 bbW_3 = *(const float4*)(bpp + 3 * REC + 8);

    const h4_t a0_0 = u2_to_h4(w01_0.x, w01_0.y), a1_0 = u2_to_h4(w01_0.z, w01_0.w);
    const h4_t a2_0 = u2_to_h4(w2_0.x, w2_0.y);
    const h4_t a0_1 = u2_to_h4(w01_1.x, w01_1.y), a1_1 = u2_to_h4(w01_1.z, w01_1.w);
    const h4_t a2_1 = u2_to_h4(w2_1.x, w2_1.y);
    const h4_t a0_2 = u2_to_h4(w01_2.x, w01_2.y), a1_2 = u2_to_h4(w01_2.z, w01_2.w);
    const h4_t a2_2 = u2_to_h4(w2_2.x, w2_2.y);
    const h4_t a0_3 = u2_to_h4(w01_3.x, w01_3.y), a1_3 = u2_to_h4(w01_3.z, w01_3.w);
    const h4_t a2_3 = u2_to_h4(w2_3.x, w2_3.y);
    const f4_t c1_0 = {bbA_0.x, bbA_0.y, bbA_0.z, bbA_0.w};
    const f4_t c2_0 = {bbB_0.x, bbB_0.y, bbB_0.z, bbB_0.w};
    const f4_t w3_0 = {bbW_0.x, bbW_0.y, bbW_0.z, bbW_0.w};
    const f4_t c1_1 = {bbA_1.x, bbA_1.y, bbA_1.z, bbA_1.w};
    const f4_t c2_1 = {bbB_1.x, bbB_1.y, bbB_1.z, bbB_1.w};
    const f4_t w3_1 = {bbW_1.x, bbW_1.y, bbW_1.z, bbW_1.w};
    const f4_t c1_2 = {bbA_2.x, bbA_2.y, bbA_2.z, bbA_2.w};
    const f4_t c2_2 = {bbB_2.x, bbB_2.y, bbB_2.z, bbB_2.w};
    const f4_t w3_2 = {bbW_2.x, bbW_2.y, bbW_2.z, bbW_2.w};
    const f4_t c1_3 = {bbA_3.x, bbA_3.y, bbA_3.z, bbA_3.w};
    const f4_t c2_3 = {bbB_3.x, bbB_3.y, bbB_3.z, bbB_3.w};
    const f4_t w3_3 = {bbW_3.x, bbW_3.y, bbW_3.z, bbW_3.w};

    acc0 += quad_chain(a0_0, a1_0, a2_0, c1_0, c2_0, w3_0,
                       a0_1, a1_1, a2_1, c1_1, c2_1, w3_1,
                       a0_2, a1_2, a2_2, c1_2, c2_2, w3_2,
                       a0_3, a1_3, a2_3, c1_3, c2_3, w3_3, bq0);
    acc1 += quad_chain(a0_0, a1_0, a2_0, c1_0, c2_0, w3_0,
                       a0_1, a1_1, a2_1, c1_1, c2_1, w3_1,
                       a0_2, a1_2, a2_2, c1_2, c2_2, w3_2,
                       a0_3, a1_3, a2_3, c1_3, c2_3, w3_3, bq1);
    acc2 += quad_chain(a0_0, a1_0, a2_0, c1_0, c2_0, w3_0,
                       a0_1, a1_1, a2_1, c1_1, c2_1, w3_1,
                       a0_2, a1_2, a2_2, c1_2, c2_2, w3_2,
                       a0_3, a1_3, a2_3, c1_3, c2_3, w3_3, bq2);
    acc3 += quad_chain(a0_0, a1_0, a2_0, c1_0, c2_0, w3_0,
                       a0_1, a1_1, a2_1, c1_1, c2_1, w3_1,
                       a0_2, a1_2, a2_2, c1_2, c2_2, w3_2,
                       a0_3, a1_3, a2_3, c1_3, c2_3, w3_3, bq3);
  }

  // Combine per-kg partials: lane (kg,col) holds rows 4kg..4kg+3's dot.
  acc0 += __shfl_down(acc0, 32); acc0 += __shfl_down(acc0, 16);
  acc1 += __shfl_down(acc1, 32); acc1 += __shfl_down(acc1, 16);
  acc2 += __shfl_down(acc2, 32); acc2 += __shfl_down(acc2, 16);
  acc3 += __shfl_down(acc3, 32); acc3 += __shfl_down(acc3, 16);

  if (kg == 0) {
    const float add = (g == 0) ? cbias : 0.f;
    atomicAdd(out + sbase +  0 + col, acc0 + add);
    atomicAdd(out + sbase + 16 + col, acc1 + add);
    atomicAdd(out + sbase + 32 + col, acc2 + add);
    atomicAdd(out + sbase + 48 + col, acc3 + add);
  }
}

// ---- correctness-only fallback (ws too small; never expected) ----
__device__ __forceinline__ float gather_weight(
    int t, int i,
    const float* __restrict__ W0, const float* __restrict__ B0,
    const float* __restrict__ W1, const float* __restrict__ B1,
    const float* __restrict__ W2, const float* __restrict__ B2,
    const float* __restrict__ W3, const float* __restrict__ B3) {
  float v = 0.f;
  if (i < 32)       { int r = i >> 1, c = i & 1;               v = W0[(16*t + r)*FEAT + 2*t + c]; }
  else if (i < 48)  {                                           v = B0[16*t + (i - 32)]; }
  else if (i < 240) { int k = i - 48, r = k >> 4, c = k & 15;   v = W1[(12*t + r)*(16*NTOW) + 16*t + c]; }
  else if (i < 252) {                                           v = B1[12*t + (i - 240)]; }
  else if (i < 348) { int k = i - 252, r = k / 12, c = k - 12*r; v = W2[(8*t + r)*(12*NTOW) + 12*t + c]; }
  else if (i < 356) {                                           v = B2[8*t + (i - 348)]; }
  else if (i < 364) {                                           v = W3[t*(8*NTOW) + 8*t + (i - 356)]; }
  else if (i == 364){                                           v = B3[t]; }
  return v;
}

__global__ void bs_fwd_slow(
    const float* __restrict__ x,
    const float* __restrict__ W0, const float* __restrict__ B0,
    const float* __restrict__ W1, const float* __restrict__ B1,
    const float* __restrict__ W2, const float* __restrict__ B2,
    const float* __restrict__ W3, const float* __restrict__ B3,
    const float* __restrict__ bias,
    float* __restrict__ out) {
  const int s = blockIdx.x * blockDim.x + threadIdx.x;
  if (s >= BATCH) return;
  float acc = bias[0];
  for (int t = 0; t < NTOW; ++t) {
    float h0[16], h1[12], h2[8];
    const float x0 = x[(size_t)s*FEAT + 2*t], x1 = x[(size_t)s*FEAT + 2*t + 1];
    for (int r = 0; r < 16; ++r)
      h0[r] = fmaxf(0.f, gather_weight(t, 2*r, W0,B0,W1,B1,W2,B2,W3,B3) * x0
                        + gather_weight(t, 2*r+1, W0,B0,W1,B1,W2,B2,W3,B3) * x1
                        + gather_weight(t, 32+r, W0,B0,W1,B1,W2,B2,W3,B3));
    for (int r = 0; r < 12; ++r) {
      float sum = gather_weight(t, 240+r, W0,B0,W1,B1,W2,B2,W3,B3);
      for (int c = 0; c < 16; ++c)
        sum += gather_weight(t, 48+16*r+c, W0,B0,W1,B1,W2,B2,W3,B3) * h0[c];
      h1[r] = fmaxf(0.f, sum);
    }
    for (int r = 0; r < 8; ++r) {
      float sum = gather_weight(t, 348+r, W0,B0,W1,B1,W2,B2,W3,B3);
      for (int c = 0; c < 12; ++c)
        sum += gather_weight(t, 252+12*r+c, W0,B0,W1,B1,W2,B2,W3,B3) * h1[c];
      h2[r] = fmaxf(0.f, sum);
    }
    float sum = gather_weight(t, 364, W0,B0,W1,B1,W2,B2,W3,B3);
    for (int c = 0; c < 8; ++c)
      sum += gather_weight(t, 356+c, W0,B0,W1,B1,W2,B2,W3,B3) * h2[c];
    acc += sum;
  }
  out[s] = acc;
}

extern "C" void kernel_launch(void* const* d_in, const int* in_sizes, int n_in,
                              void* d_out, int out_size, void* d_ws, size_t ws_size,
                              hipStream_t stream) {
  const float* x    = (const float*)d_in[0];
  const float* W0   = (const float*)d_in[1];
  const float* B0   = (const float*)d_in[2];
  const float* W1   = (const float*)d_in[3];
  const float* B1   = (const float*)d_in[4];
  const float* W2   = (const float*)d_in[5];
  const float* B2   = (const float*)d_in[6];
  const float* W3   = (const float*)d_in[7];
  const float* B3   = (const float*)d_in[8];
  const float* bias = (const float*)d_in[9];
  float* out = (float*)d_out;

  const size_t packBytes = ((size_t)NTOW * REC + 1) * sizeof(uint32_t);

  if (ws_size >= packBytes) {
    uint32_t* pack = (uint32_t*)d_ws;
    // pack_frags also zeroes out[] (atomics accumulate; shape_loss stays 0).
    pack_frags<<<NTOW, 64, 0, stream>>>(W0, B0, W1, B1, W2, B2, W3, B3, bias, pack, out);
    const int blocks = (BATCH / 256) * 8;         // 1024 blocks
    bs_mfma<<<blocks, 256, 0, stream>>>(x, pack, out);
  } else {
    (void)hipMemsetAsync(d_out, 0, (size_t)out_size * sizeof(float), stream);
    bs_fwd_slow<<<BATCH / 256, 256, 0, stream>>>(x, W0, B0, W1, B1, W2, B2, W3, B3, bias, out);
  }
}

// Round 20
// 29.241 us; speedup vs baseline: 1.0788x; 1.0788x over previous
//
#include <hip/hip_runtime.h>
#include <stdint.h>

// Blocksparse Deep ReLU GAM forward via chained f16 MFMA.
// 128 towers, each 2->16->12->8->1 MLP over input pair (2t, 2t+1);
// out[s] = sum_t tower_t(x[s]) + bias. shape_loss output = zeros(128).
//
// v_mfma_f32_16x16x16_f16 D layout (row=(lane>>4)*4+reg, col=lane&15)
// equals the B layout (k=(lane>>4)*4+i, col=lane&15), so Y = W·X chains
// layer-to-layer with only lane-local relu + f32->f16 cvt.
//
// Round 20: oct_chain — 8-way chain interleave. r19 (L3 on VALU)
// regressed: it cut MFMA issue (15% busy, not the constraint) and
// added VALU+shuffles. Reverted to r18's 4-MFMA chain. r18's quad
// (4-way ILP) gained only 1.7us -> the compiler doesn't fully overlap
// the four independent quad_chain calls. Occupancy is GRID-capped
// (1024 blocks = 4 waves/SIMD), so VGPR up to 128 is free: oct_chain
// runs 4 towers x 2 sample-tiles in lockstep = 8 independent MFMAs per
// layer step. Liveness ~= 64 (weights, shared across both u) + 32
// (8 D-frags) + misc ~= 110 < 128. Rolled p-loop still fences load
// hoisting (r11 lesson); all values named scalars (rule #20).
// Proven structure: same-g blocks (L1 weights), launch_bounds(256,4),
// b1/b2 as C operands, interleaved bb, parallel b3 reduce, out-zeroing
// in pack_frags.
//
// 4-tower shared B0: lane (kg,col) carries B0 rows 4kg..4kg+2 =
// {x[s][2(tb+kg)], x[s][2(tb+kg)+1], 1}; tower tb+j's A0 is nonzero only
// in k-columns 4j..4j+2, so one coalesced all-lane x load feeds 4 towers.
//
// Bias: b0 -> A0 k=4j+2 (homogeneous coord); b1 -> C of L1 MFMA;
// b2 -> C of L2 MFMA; sum_t b3[t] + bias -> one scalar at the end.

constexpr int BATCH = 32768;
constexpr int FEAT  = 256;
constexpr int NTOW  = 128;
constexpr int OUTN  = BATCH + NTOW;   // out + shape_loss

constexpr int REC = 544;  // dwords per tower record (2176 B, 16B-aligned)
// [0,512) = 64 lanes x 8 dwords {a0.lo,a0.hi,a1.lo,a1.hi,a2.lo,a2.hi,
// a3.lo,a3.hi}; [512,544) = bb: per kg {b1[4kg..4kg+3], b2[4kg..4kg+3]}.
constexpr int OFF_BB = 512;

typedef _Float16 h4_t __attribute__((ext_vector_type(4)));
typedef __fp16   hp2_t __attribute__((ext_vector_type(2)));
typedef float    f4_t __attribute__((ext_vector_type(4)));

static __device__ __forceinline__ h4_t u2_to_h4(uint32_t lo, uint32_t hi) {
  union { uint2 u; h4_t h; } cv; cv.u.x = lo; cv.u.y = hi; return cv.h;
}
static __device__ __forceinline__ void h4_to_u2(h4_t v, uint32_t* d) {
  union { h4_t h; uint2 u; } cv; cv.h = v; d[0] = cv.u.x; d[1] = cv.u.y;
}
// pack 4 f32 -> 4 f16 (2x v_cvt_pkrtz) then packed relu (v_pk_max_f16 x2).
// relu(cvt(x)) == cvt(relu(x)): RTZ preserves sign; -0 is harmless in dots.
static __device__ __forceinline__ h4_t relu_pack4(const f4_t d) {
  const hp2_t lo = __builtin_amdgcn_cvt_pkrtz(d[0], d[1]);
  const hp2_t hi = __builtin_amdgcn_cvt_pkrtz(d[2], d[3]);
  h4_t r;
  r[0] = (_Float16)lo[0]; r[1] = (_Float16)lo[1];
  r[2] = (_Float16)hi[0]; r[3] = (_Float16)hi[1];
  const h4_t z = {(_Float16)0.f, (_Float16)0.f, (_Float16)0.f, (_Float16)0.f};
  return __builtin_elementwise_max(r, z);
}
// Build a B0 fragment from an x pair: {x0, x1, 1, 0}.
static __device__ __forceinline__ h4_t make_b0(const float* __restrict__ p) {
  const float2 xv = *(const float2*)p;
  const hp2_t xh = __builtin_amdgcn_cvt_pkrtz(xv.x, xv.y);
  h4_t b;
  b[0] = (_Float16)xh[0]; b[1] = (_Float16)xh[1];
  b[2] = (_Float16)1.0f;  b[3] = (_Float16)0.0f;
  return b;
}

#define MFMA16(A, B, C) __builtin_amdgcn_mfma_f32_16x16x16f16((A), (B), (C), 0, 0, 0)

// Four towers x TWO sample tiles, layers in lockstep: each layer step
// issues 8 independent MFMAs + 8 relus -> 8-way ILP fully covers the
// MFMA->relu->MFMA dependency latency. All values named (SSA).
// Returns {sumA, sumB} (lane row 0 only is nonzero).
static __device__ __forceinline__ float2 oct_chain(
    h4_t a0_0, h4_t a1_0, h4_t a2_0, h4_t a3_0, f4_t c1_0, f4_t c2_0,
    h4_t a0_1, h4_t a1_1, h4_t a2_1, h4_t a3_1, f4_t c1_1, f4_t c2_1,
    h4_t a0_2, h4_t a1_2, h4_t a2_2, h4_t a3_2, f4_t c1_2, f4_t c2_2,
    h4_t a0_3, h4_t a1_3, h4_t a2_3, h4_t a3_3, f4_t c1_3, f4_t c2_3,
    h4_t bA, h4_t bB) {
  const f4_t zc = {0.f, 0.f, 0.f, 0.f};
  const f4_t dA0_0 = MFMA16(a0_0, bA, zc);
  const f4_t dB0_0 = MFMA16(a0_0, bB, zc);
  const f4_t dA0_1 = MFMA16(a0_1, bA, zc);
  const f4_t dB0_1 = MFMA16(a0_1, bB, zc);
  const f4_t dA0_2 = MFMA16(a0_2, bA, zc);
  const f4_t dB0_2 = MFMA16(a0_2, bB, zc);
  const f4_t dA0_3 = MFMA16(a0_3, bA, zc);
  const f4_t dB0_3 = MFMA16(a0_3, bB, zc);
  const h4_t hA0_0 = relu_pack4(dA0_0);
  const h4_t hB0_0 = relu_pack4(dB0_0);
  const h4_t hA0_1 = relu_pack4(dA0_1);
  const h4_t hB0_1 = relu_pack4(dB0_1);
  const h4_t hA0_2 = relu_pack4(dA0_2);
  const h4_t hB0_2 = relu_pack4(dB0_2);
  const h4_t hA0_3 = relu_pack4(dA0_3);
  const h4_t hB0_3 = relu_pack4(dB0_3);
  const f4_t dA1_0 = MFMA16(a1_0, hA0_0, c1_0);
  const f4_t dB1_0 = MFMA16(a1_0, hB0_0, c1_0);
  const f4_t dA1_1 = MFMA16(a1_1, hA0_1, c1_1);
  const f4_t dB1_1 = MFMA16(a1_1, hB0_1, c1_1);
  const f4_t dA1_2 = MFMA16(a1_2, hA0_2, c1_2);
  const f4_t dB1_2 = MFMA16(a1_2, hB0_2, c1_2);
  const f4_t dA1_3 = MFMA16(a1_3, hA0_3, c1_3);
  const f4_t dB1_3 = MFMA16(a1_3, hB0_3, c1_3);
  const h4_t hA1_0 = relu_pack4(dA1_0);
  const h4_t hB1_0 = relu_pack4(dB1_0);
  const h4_t hA1_1 = relu_pack4(dA1_1);
  const h4_t hB1_1 = relu_pack4(dB1_1);
  const h4_t hA1_2 = relu_pack4(dA1_2);
  const h4_t hB1_2 = relu_pack4(dB1_2);
  const h4_t hA1_3 = relu_pack4(dA1_3);
  const h4_t hB1_3 = relu_pack4(dB1_3);
  const f4_t dA2_0 = MFMA16(a2_0, hA1_0, c2_0);
  const f4_t dB2_0 = MFMA16(a2_0, hB1_0, c2_0);
  const f4_t dA2_1 = MFMA16(a2_1, hA1_1, c2_1);
  const f4_t dB2_1 = MFMA16(a2_1, hB1_1, c2_1);
  const f4_t dA2_2 = MFMA16(a2_2, hA1_2, c2_2);
  const f4_t dB2_2 = MFMA16(a2_2, hB1_2, c2_2);
  const f4_t dA2_3 = MFMA16(a2_3, hA1_3, c2_3);
  const f4_t dB2_3 = MFMA16(a2_3, hB1_3, c2_3);
  const h4_t hA2_0 = relu_pack4(dA2_0);
  const h4_t hB2_0 = relu_pack4(dB2_0);
  const h4_t hA2_1 = relu_pack4(dA2_1);
  const h4_t hB2_1 = relu_pack4(dB2_1);
  const h4_t hA2_2 = relu_pack4(dA2_2);
  const h4_t hB2_2 = relu_pack4(dB2_2);
  const h4_t hA2_3 = relu_pack4(dA2_3);
  const h4_t hB2_3 = relu_pack4(dB2_3);
  const f4_t dA3_0 = MFMA16(a3_0, hA2_0, zc);
  const f4_t dB3_0 = MFMA16(a3_0, hB2_0, zc);
  const f4_t dA3_1 = MFMA16(a3_1, hA2_1, zc);
  const f4_t dB3_1 = MFMA16(a3_1, hB2_1, zc);
  const f4_t dA3_2 = MFMA16(a3_2, hA2_2, zc);
  const f4_t dB3_2 = MFMA16(a3_2, hB2_2, zc);
  const f4_t dA3_3 = MFMA16(a3_3, hA2_3, zc);
  const f4_t dB3_3 = MFMA16(a3_3, hB2_3, zc);
  // Only row 0 (kg==0, reg 0) of each L3 product is nonzero.
  float2 r;
  r.x = (dA3_0[0] + dA3_1[0]) + (dA3_2[0] + dA3_3[0]);
  r.y = (dB3_0[0] + dB3_1[0]) + (dB3_2[0] + dB3_3[0]);
  return r;
}

__global__ void pack_frags(
    const float* __restrict__ W0, const float* __restrict__ B0,
    const float* __restrict__ W1, const float* __restrict__ B1,
    const float* __restrict__ W2, const float* __restrict__ B2,
    const float* __restrict__ W3, const float* __restrict__ B3,
    const float* __restrict__ bias, uint32_t* __restrict__ pack,
    float* __restrict__ out) {
  const int t   = blockIdx.x;
  const int l   = threadIdx.x;      // 64 threads = 64 lanes
  const int row = l & 15;           // A-frag row  = lane&15
  const int kg  = l >> 4;           // A-frag k    = (lane>>4)*4 + r
  uint32_t* rec = pack + t * REC;

  // Zero the output buffer (out[0:BATCH] accumulated by atomics;
  // shape_loss[BATCH:BATCH+NTOW] stays 0). Grid-stride over all blocks.
  for (int i = t * 64 + l; i < OUTN; i += NTOW * 64) out[i] = 0.f;

  h4_t a0, a1, a2, a3;
#pragma unroll
  for (int r = 0; r < 4; ++r) {
    const int k = kg * 4 + r;
    // A0: tower t occupies k-columns 4*(t&3) .. 4*(t&3)+2.
    float v0 = 0.f;
    if (kg == (t & 3)) {
      if (r < 2)       v0 = W0[(16*t + row) * FEAT + 2*t + r];
      else if (r == 2) v0 = B0[16*t + row];
    }
    a0[r] = (_Float16)v0;

    float v1 = 0.f;
    if (row < 12)    v1 = W1[(12*t + row) * (16*NTOW) + 16*t + k];
    a1[r] = (_Float16)v1;

    float v2 = 0.f;
    if (row < 8 && k < 12) v2 = W2[(8*t + row) * (12*NTOW) + 12*t + k];
    a2[r] = (_Float16)v2;

    float v3 = 0.f;
    if (row == 0 && k < 8) v3 = W3[t * (8*NTOW) + 8*t + k];
    a3[r] = (_Float16)v3;
  }
  uint32_t* lrec = rec + 8 * l;
  h4_to_u2(a0, lrec + 0);
  h4_to_u2(a1, lrec + 2);
  h4_to_u2(a2, lrec + 4);
  h4_to_u2(a3, lrec + 6);

  if (l < 16) {
    // Interleaved bb layout: per kg-group {b1[4kg..4kg+3], b2[...]}.
    const float b1v = (l < 12) ? B1[12*t + l] : 0.f;
    const float b2v = (l < 8) ? B2[8*t + l] : 0.f;
    rec[OFF_BB + (l >> 2) * 8 +     (l & 3)] = __float_as_uint(b1v);
    rec[OFF_BB + (l >> 2) * 8 + 4 + (l & 3)] = __float_as_uint(b2v);
  }
  if (t == 0) {
    // Parallel b3+bias sum: 64 lanes load 2 each, wave shuffle-reduce.
    float s = B3[l] + B3[64 + l];
#pragma unroll
    for (int m = 32; m >= 1; m >>= 1) s += __shfl_xor(s, m);
    if (l == 0) pack[NTOW * REC] = __float_as_uint(s + bias[0]);
  }
}

// One block: tower group g (16 towers) x 256 samples (4 waves x 64).
// All 4 waves stream the SAME 16 tower records -> L1-resident weights.
__global__ __launch_bounds__(256, 4) void bs_mfma(
    const float* __restrict__ x, const uint32_t* __restrict__ pack,
    float* __restrict__ out) {
  const int warp  = threadIdx.x >> 6;
  const int lane  = threadIdx.x & 63;
  const int col   = lane & 15;       // sample within tile
  const int kg    = lane >> 4;
  const int g     = blockIdx.x & 7;  // tower group: towers [16g, 16g+16)
  const int tile  = blockIdx.x >> 3;
  const int sbase = tile * 256 + warp * 64;

  const float cbias = __uint_as_float(pack[NTOW * REC]);

  // Per-lane x base: sample row (sbase+col), feature 2*(16g + kg).
  const float* __restrict__ xb =
      x + (size_t)(sbase + col) * FEAT + 2 * (g * 16 + kg);

  const uint32_t* __restrict__ fp = pack + (size_t)(g * 16) * REC + 8 * lane;
  const uint32_t* __restrict__ bp = pack + (size_t)(g * 16) * REC + OFF_BB + kg * 8;

  float acc0 = 0.f, acc1 = 0.f, acc2 = 0.f, acc3 = 0.f;

#pragma unroll 1
  for (int p = 0; p < 4; ++p) {      // packs of 4 towers — ROLLED
    // B0 fragments for this pack's 4 sample tiles (shared by the pack's
    // 4 towers). Named scalars -> guaranteed register allocation.
    const float* __restrict__ xp = xb + 8 * p;
    const h4_t bq0 = make_b0(xp + (size_t)0 * 16 * FEAT);
    const h4_t bq1 = make_b0(xp + (size_t)1 * 16 * FEAT);
    const h4_t bq2 = make_b0(xp + (size_t)2 * 16 * FEAT);
    const h4_t bq3 = make_b0(xp + (size_t)3 * 16 * FEAT);

    // Load all 4 towers' fragments (named; ~64 VGPR of weight state).
    const uint32_t* __restrict__ fpp = fp + (size_t)(4 * p) * REC;
    const uint32_t* __restrict__ bpp = bp + (size_t)(4 * p) * REC;
    const uint4  w01_0 = *(const uint4*)(fpp + 0 * REC);
    const uint4  w23_0 = *(const uint4*)(fpp + 0 * REC + 4);
    const uint4  w01_1 = *(const uint4*)(fpp + 1 * REC);
    const uint4  w23_1 = *(const uint4*)(fpp + 1 * REC + 4);
    const uint4  w01_2 = *(const uint4*)(fpp + 2 * REC);
    const uint4  w23_2 = *(const uint4*)(fpp + 2 * REC + 4);
    const uint4  w01_3 = *(const uint4*)(fpp + 3 * REC);
    const uint4  w23_3 = *(const uint4*)(fpp + 3 * REC + 4);
    const float4 bbA_0 = *(const float4*)(bpp + 0 * REC);
    const float4 bbB_0 = *(const float4*)(bpp + 0 * REC + 4);
    const float4 bbA_1 = *(const float4*)(bpp + 1 * REC);
    const float4 bbB_1 = *(const float4*)(bpp + 1 * REC + 4);
    const float4 bbA_2 = *(const float4*)(bpp + 2 * REC);
    const float4 bbB_2 = *(const float4*)(bpp + 2 * REC + 4);
    const float4 bbA_3 = *(const float4*)(bpp + 3 * REC);
    const float4 bbB_3 = *(const float4*)(bpp + 3 * REC + 4);

    const h4_t a0_0 = u2_to_h4(w01_0.x, w01_0.y), a1_0 = u2_to_h4(w01_0.z, w01_0.w);
    const h4_t a2_0 = u2_to_h4(w23_0.x, w23_0.y), a3_0 = u2_to_h4(w23_0.z, w23_0.w);
    const h4_t a0_1 = u2_to_h4(w01_1.x, w01_1.y), a1_1 = u2_to_h4(w01_1.z, w01_1.w);
    const h4_t a2_1 = u2_to_h4(w23_1.x, w23_1.y), a3_1 = u2_to_h4(w23_1.z, w23_1.w);
    const h4_t a0_2 = u2_to_h4(w01_2.x, w01_2.y), a1_2 = u2_to_h4(w01_2.z, w01_2.w);
    const h4_t a2_2 = u2_to_h4(w23_2.x, w23_2.y), a3_2 = u2_to_h4(w23_2.z, w23_2.w);
    const h4_t a0_3 = u2_to_h4(w01_3.x, w01_3.y), a1_3 = u2_to_h4(w01_3.z, w01_3.w);
    const h4_t a2_3 = u2_to_h4(w23_3.x, w23_3.y), a3_3 = u2_to_h4(w23_3.z, w23_3.w);
    const f4_t c1_0 = {bbA_0.x, bbA_0.y, bbA_0.z, bbA_0.w};
    const f4_t c2_0 = {bbB_0.x, bbB_0.y, bbB_0.z, bbB_0.w};
    const f4_t c1_1 = {bbA_1.x, bbA_1.y, bbA_1.z, bbA_1.w};
    const f4_t c2_1 = {bbB_1.x, bbB_1.y, bbB_1.z, bbB_1.w};
    const f4_t c1_2 = {bbA_2.x, bbA_2.y, bbA_2.z, bbA_2.w};
    const f4_t c2_2 = {bbB_2.x, bbB_2.y, bbB_2.z, bbB_2.w};
    const f4_t c1_3 = {bbA_3.x, bbA_3.y, bbA_3.z, bbA_3.w};
    const f4_t c2_3 = {bbB_3.x, bbB_3.y, bbB_3.z, bbB_3.w};

    const float2 r01 = oct_chain(a0_0, a1_0, a2_0, a3_0, c1_0, c2_0,
                                 a0_1, a1_1, a2_1, a3_1, c1_1, c2_1,
                                 a0_2, a1_2, a2_2, a3_2, c1_2, c2_2,
                                 a0_3, a1_3, a2_3, a3_3, c1_3, c2_3,
                                 bq0, bq1);
    acc0 += r01.x; acc1 += r01.y;
    const float2 r23 = oct_chain(a0_0, a1_0, a2_0, a3_0, c1_0, c2_0,
                                 a0_1, a1_1, a2_1, a3_1, c1_1, c2_1,
                                 a0_2, a1_2, a2_2, a3_2, c1_2, c2_2,
                                 a0_3, a1_3, a2_3, a3_3, c1_3, c2_3,
                                 bq2, bq3);
    acc2 += r23.x; acc3 += r23.y;
  }

  if (kg == 0) {
    const float add = (g == 0) ? cbias : 0.f;
    atomicAdd(out + sbase +  0 + col, acc0 + add);
    atomicAdd(out + sbase + 16 + col, acc1 + add);
    atomicAdd(out + sbase + 32 + col, acc2 + add);
    atomicAdd(out + sbase + 48 + col, acc3 + add);
  }
}

// ---- correctness-only fallback (ws too small; never expected) ----
__device__ __forceinline__ float gather_weight(
    int t, int i,
    const float* __restrict__ W0, const float* __restrict__ B0,
    const float* __restrict__ W1, const float* __restrict__ B1,
    const float* __restrict__ W2, const float* __restrict__ B2,
    const float* __restrict__ W3, const float* __restrict__ B3) {
  float v = 0.f;
  if (i < 32)       { int r = i >> 1, c = i & 1;               v = W0[(16*t + r)*FEAT + 2*t + c]; }
  else if (i < 48)  {                                           v = B0[16*t + (i - 32)]; }
  else if (i < 240) { int k = i - 48, r = k >> 4, c = k & 15;   v = W1[(12*t + r)*(16*NTOW) + 16*t + c]; }
  else if (i < 252) {                                           v = B1[12*t + (i - 240)]; }
  else if (i < 348) { int k = i - 252, r = k / 12, c = k - 12*r; v = W2[(8*t + r)*(12*NTOW) + 12*t + c]; }
  else if (i < 356) {                                           v = B2[8*t + (i - 348)]; }
  else if (i < 364) {                                           v = W3[t*(8*NTOW) + 8*t + (i - 356)]; }
  else if (i == 364){                                           v = B3[t]; }
  return v;
}

__global__ void bs_fwd_slow(
    const float* __restrict__ x,
    const float* __restrict__ W0, const float* __restrict__ B0,
    const float* __restrict__ W1, const float* __restrict__ B1,
    const float* __restrict__ W2, const float* __restrict__ B2,
    const float* __restrict__ W3, const float* __restrict__ B3,
    const float* __restrict__ bias,
    float* __restrict__ out) {
  const int s = blockIdx.x * blockDim.x + threadIdx.x;
  if (s >= BATCH) return;
  float acc = bias[0];
  for (int t = 0; t < NTOW; ++t) {
    float h0[16], h1[12], h2[8];
    const float x0 = x[(size_t)s*FEAT + 2*t], x1 = x[(size_t)s*FEAT + 2*t + 1];
    for (int r = 0; r < 16; ++r)
      h0[r] = fmaxf(0.f, gather_weight(t, 2*r, W0,B0,W1,B1,W2,B2,W3,B3) * x0
                        + gather_weight(t, 2*r+1, W0,B0,W1,B1,W2,B2,W3,B3) * x1
                        + gather_weight(t, 32+r, W0,B0,W1,B1,W2,B2,W3,B3));
    for (int r = 0; r < 12; ++r) {
      float sum = gather_weight(t, 240+r, W0,B0,W1,B1,W2,B2,W3,B3);
      for (int c = 0; c < 16; ++c)
        sum += gather_weight(t, 48+16*r+c, W0,B0,W1,B1,W2,B2,W3,B3) * h0[c];
      h1[r] = fmaxf(0.f, sum);
    }
    for (int r = 0; r < 8; ++r) {
      float sum = gather_weight(t, 348+r, W0,B0,W1,B1,W2,B2,W3,B3);
      for (int c = 0; c < 12; ++c)
        sum += gather_weight(t, 252+12*r+c, W0,B0,W1,B1,W2,B2,W3,B3) * h1[c];
      h2[r] = fmaxf(0.f, sum);
    }
    float sum = gather_weight(t, 364, W0,B0,W1,B1,W2,B2,W3,B3);
    for (int c = 0; c < 8; ++c)
      sum += gather_weight(t, 356+c, W0,B0,W1,B1,W2,B2,W3,B3) * h2[c];
    acc += sum;
  }
  out[s] = acc;
}

extern "C" void kernel_launch(void* const* d_in, const int* in_sizes, int n_in,
                              void* d_out, int out_size, void* d_ws, size_t ws_size,
                              hipStream_t stream) {
  const float* x    = (const float*)d_in[0];
  const float* W0   = (const float*)d_in[1];
  const float* B0   = (const float*)d_in[2];
  const float* W1   = (const float*)d_in[3];
  const float* B1   = (const float*)d_in[4];
  const float* W2   = (const float*)d_in[5];
  const float* B2   = (const float*)d_in[6];
  const float* W3   = (const float*)d_in[7];
  const float* B3   = (const float*)d_in[8];
  const float* bias = (const float*)d_in[9];
  float* out = (float*)d_out;

  const size_t packBytes = ((size_t)NTOW * REC + 1) * sizeof(uint32_t);

  if (ws_size >= packBytes) {
    uint32_t* pack = (uint32_t*)d_ws;
    // pack_frags also zeroes out[] (atomics accumulate; shape_loss stays 0).
    pack_frags<<<NTOW, 64, 0, stream>>>(W0, B0, W1, B1, W2, B2, W3, B3, bias, pack, out);
    const int blocks = (BATCH / 256) * 8;         // 1024 blocks
    bs_mfma<<<blocks, 256, 0, stream>>>(x, pack, out);
  } else {
    (void)hipMemsetAsync(d_out, 0, (size_t)out_size * sizeof(float), stream);
    bs_fwd_slow<<<BATCH / 256, 256, 0, stream>>>(x, W0, B0, W1, B1, W2, B2, W3, B3, bias, out);
  }
}

// Round 21
// 29.213 us; speedup vs baseline: 1.0799x; 1.0010x over previous
//
#include <hip/hip_runtime.h>
#include <stdint.h>

// Blocksparse Deep ReLU GAM forward via chained f16 MFMA.
// 128 towers, each 2->16->12->8->1 MLP over input pair (2t, 2t+1);
// out[s] = sum_t tower_t(x[s]) + bias. shape_loss output = zeros(128).
//
// v_mfma_f32_16x16x16_f16 D layout (row=(lane>>4)*4+reg, col=lane&15)
// equals the B layout (k=(lane>>4)*4+i, col=lane&15), so Y = W·X chains
// layer-to-layer with only lane-local relu + f32->f16 cvt.
//
// Round 21: r20 (oct_chain, 29.24us best) + amdgpu_waves_per_eu(4,4).
// The grid (1024 blocks = 4 blocks/CU) caps occupancy at 4 waves/SIMD
// no matter what, but the allocator defaults toward 8 waves/SIMD
// (~64 VGPR) and strands registers 64..128. The attribute tells it
// occupancy is exactly 4 waves/EU so it may use the full 128-VGPR
// budget -> scheduler can hoist next-pack weight loads / keep both
// oct_chains' state live. r10's null test of this attribute was
// confounded by rule-#20 array scratch; r20's all-named-scalar body
// gives it a fair test. If neutral: structure is at its plateau.
//
// Proven structure: oct_chain 8-way lockstep ILP, same-g blocks (L1
// weights), rolled pack loop (liveness fence), named scalars only,
// b1/b2 as C operands, interleaved bb, parallel b3 reduce, out-zeroing
// in pack_frags.
//
// 4-tower shared B0: lane (kg,col) carries B0 rows 4kg..4kg+2 =
// {x[s][2(tb+kg)], x[s][2(tb+kg)+1], 1}; tower tb+j's A0 is nonzero only
// in k-columns 4j..4j+2, so one coalesced all-lane x load feeds 4 towers.
//
// Bias: b0 -> A0 k=4j+2 (homogeneous coord); b1 -> C of L1 MFMA;
// b2 -> C of L2 MFMA; sum_t b3[t] + bias -> one scalar at the end.

constexpr int BATCH = 32768;
constexpr int FEAT  = 256;
constexpr int NTOW  = 128;
constexpr int OUTN  = BATCH + NTOW;   // out + shape_loss

constexpr int REC = 544;  // dwords per tower record (2176 B, 16B-aligned)
// [0,512) = 64 lanes x 8 dwords {a0.lo,a0.hi,a1.lo,a1.hi,a2.lo,a2.hi,
// a3.lo,a3.hi}; [512,544) = bb: per kg {b1[4kg..4kg+3], b2[4kg..4kg+3]}.
constexpr int OFF_BB = 512;

typedef _Float16 h4_t __attribute__((ext_vector_type(4)));
typedef __fp16   hp2_t __attribute__((ext_vector_type(2)));
typedef float    f4_t __attribute__((ext_vector_type(4)));

static __device__ __forceinline__ h4_t u2_to_h4(uint32_t lo, uint32_t hi) {
  union { uint2 u; h4_t h; } cv; cv.u.x = lo; cv.u.y = hi; return cv.h;
}
static __device__ __forceinline__ void h4_to_u2(h4_t v, uint32_t* d) {
  union { h4_t h; uint2 u; } cv; cv.h = v; d[0] = cv.u.x; d[1] = cv.u.y;
}
// pack 4 f32 -> 4 f16 (2x v_cvt_pkrtz) then packed relu (v_pk_max_f16 x2).
// relu(cvt(x)) == cvt(relu(x)): RTZ preserves sign; -0 is harmless in dots.
static __device__ __forceinline__ h4_t relu_pack4(const f4_t d) {
  const hp2_t lo = __builtin_amdgcn_cvt_pkrtz(d[0], d[1]);
  const hp2_t hi = __builtin_amdgcn_cvt_pkrtz(d[2], d[3]);
  h4_t r;
  r[0] = (_Float16)lo[0]; r[1] = (_Float16)lo[1];
  r[2] = (_Float16)hi[0]; r[3] = (_Float16)hi[1];
  const h4_t z = {(_Float16)0.f, (_Float16)0.f, (_Float16)0.f, (_Float16)0.f};
  return __builtin_elementwise_max(r, z);
}
// Build a B0 fragment from an x pair: {x0, x1, 1, 0}.
static __device__ __forceinline__ h4_t make_b0(const float* __restrict__ p) {
  const float2 xv = *(const float2*)p;
  const hp2_t xh = __builtin_amdgcn_cvt_pkrtz(xv.x, xv.y);
  h4_t b;
  b[0] = (_Float16)xh[0]; b[1] = (_Float16)xh[1];
  b[2] = (_Float16)1.0f;  b[3] = (_Float16)0.0f;
  return b;
}

#define MFMA16(A, B, C) __builtin_amdgcn_mfma_f32_16x16x16f16((A), (B), (C), 0, 0, 0)

// Four towers x TWO sample tiles, layers in lockstep: each layer step
// issues 8 independent MFMAs + 8 relus -> 8-way ILP covers the
// MFMA->relu->MFMA dependency latency. All values named (SSA).
// Returns {sumA, sumB} (lane row 0 only is nonzero).
static __device__ __forceinline__ float2 oct_chain(
    h4_t a0_0, h4_t a1_0, h4_t a2_0, h4_t a3_0, f4_t c1_0, f4_t c2_0,
    h4_t a0_1, h4_t a1_1, h4_t a2_1, h4_t a3_1, f4_t c1_1, f4_t c2_1,
    h4_t a0_2, h4_t a1_2, h4_t a2_2, h4_t a3_2, f4_t c1_2, f4_t c2_2,
    h4_t a0_3, h4_t a1_3, h4_t a2_3, h4_t a3_3, f4_t c1_3, f4_t c2_3,
    h4_t bA, h4_t bB) {
  const f4_t zc = {0.f, 0.f, 0.f, 0.f};
  const f4_t dA0_0 = MFMA16(a0_0, bA, zc);
  const f4_t dB0_0 = MFMA16(a0_0, bB, zc);
  const f4_t dA0_1 = MFMA16(a0_1, bA, zc);
  const f4_t dB0_1 = MFMA16(a0_1, bB, zc);
  const f4_t dA0_2 = MFMA16(a0_2, bA, zc);
  const f4_t dB0_2 = MFMA16(a0_2, bB, zc);
  const f4_t dA0_3 = MFMA16(a0_3, bA, zc);
  const f4_t dB0_3 = MFMA16(a0_3, bB, zc);
  const h4_t hA0_0 = relu_pack4(dA0_0);
  const h4_t hB0_0 = relu_pack4(dB0_0);
  const h4_t hA0_1 = relu_pack4(dA0_1);
  const h4_t hB0_1 = relu_pack4(dB0_1);
  const h4_t hA0_2 = relu_pack4(dA0_2);
  const h4_t hB0_2 = relu_pack4(dB0_2);
  const h4_t hA0_3 = relu_pack4(dA0_3);
  const h4_t hB0_3 = relu_pack4(dB0_3);
  const f4_t dA1_0 = MFMA16(a1_0, hA0_0, c1_0);
  const f4_t dB1_0 = MFMA16(a1_0, hB0_0, c1_0);
  const f4_t dA1_1 = MFMA16(a1_1, hA0_1, c1_1);
  const f4_t dB1_1 = MFMA16(a1_1, hB0_1, c1_1);
  const f4_t dA1_2 = MFMA16(a1_2, hA0_2, c1_2);
  const f4_t dB1_2 = MFMA16(a1_2, hB0_2, c1_2);
  const f4_t dA1_3 = MFMA16(a1_3, hA0_3, c1_3);
  const f4_t dB1_3 = MFMA16(a1_3, hB0_3, c1_3);
  const h4_t hA1_0 = relu_pack4(dA1_0);
  const h4_t hB1_0 = relu_pack4(dB1_0);
  const h4_t hA1_1 = relu_pack4(dA1_1);
  const h4_t hB1_1 = relu_pack4(dB1_1);
  const h4_t hA1_2 = relu_pack4(dA1_2);
  const h4_t hB1_2 = relu_pack4(dB1_2);
  const h4_t hA1_3 = relu_pack4(dA1_3);
  const h4_t hB1_3 = relu_pack4(dB1_3);
  const f4_t dA2_0 = MFMA16(a2_0, hA1_0, c2_0);
  const f4_t dB2_0 = MFMA16(a2_0, hB1_0, c2_0);
  const f4_t dA2_1 = MFMA16(a2_1, hA1_1, c2_1);
  const f4_t dB2_1 = MFMA16(a2_1, hB1_1, c2_1);
  const f4_t dA2_2 = MFMA16(a2_2, hA1_2, c2_2);
  const f4_t dB2_2 = MFMA16(a2_2, hB1_2, c2_2);
  const f4_t dA2_3 = MFMA16(a2_3, hA1_3, c2_3);
  const f4_t dB2_3 = MFMA16(a2_3, hB1_3, c2_3);
  const h4_t hA2_0 = relu_pack4(dA2_0);
  const h4_t hB2_0 = relu_pack4(dB2_0);
  const h4_t hA2_1 = relu_pack4(dA2_1);
  const h4_t hB2_1 = relu_pack4(dB2_1);
  const h4_t hA2_2 = relu_pack4(dA2_2);
  const h4_t hB2_2 = relu_pack4(dB2_2);
  const h4_t hA2_3 = relu_pack4(dA2_3);
  const h4_t hB2_3 = relu_pack4(dB2_3);
  const f4_t dA3_0 = MFMA16(a3_0, hA2_0, zc);
  const f4_t dB3_0 = MFMA16(a3_0, hB2_0, zc);
  const f4_t dA3_1 = MFMA16(a3_1, hA2_1, zc);
  const f4_t dB3_1 = MFMA16(a3_1, hB2_1, zc);
  const f4_t dA3_2 = MFMA16(a3_2, hA2_2, zc);
  const f4_t dB3_2 = MFMA16(a3_2, hB2_2, zc);
  const f4_t dA3_3 = MFMA16(a3_3, hA2_3, zc);
  const f4_t dB3_3 = MFMA16(a3_3, hB2_3, zc);
  // Only row 0 (kg==0, reg 0) of each L3 product is nonzero.
  float2 r;
  r.x = (dA3_0[0] + dA3_1[0]) + (dA3_2[0] + dA3_3[0]);
  r.y = (dB3_0[0] + dB3_1[0]) + (dB3_2[0] + dB3_3[0]);
  return r;
}

__global__ void pack_frags(
    const float* __restrict__ W0, const float* __restrict__ B0,
    const float* __restrict__ W1, const float* __restrict__ B1,
    const float* __restrict__ W2, const float* __restrict__ B2,
    const float* __restrict__ W3, const float* __restrict__ B3,
    const float* __restrict__ bias, uint32_t* __restrict__ pack,
    float* __restrict__ out) {
  const int t   = blockIdx.x;
  const int l   = threadIdx.x;      // 64 threads = 64 lanes
  const int row = l & 15;           // A-frag row  = lane&15
  const int kg  = l >> 4;           // A-frag k    = (lane>>4)*4 + r
  uint32_t* rec = pack + t * REC;

  // Zero the output buffer (out[0:BATCH] accumulated by atomics;
  // shape_loss[BATCH:BATCH+NTOW] stays 0). Grid-stride over all blocks.
  for (int i = t * 64 + l; i < OUTN; i += NTOW * 64) out[i] = 0.f;

  h4_t a0, a1, a2, a3;
#pragma unroll
  for (int r = 0; r < 4; ++r) {
    const int k = kg * 4 + r;
    // A0: tower t occupies k-columns 4*(t&3) .. 4*(t&3)+2.
    float v0 = 0.f;
    if (kg == (t & 3)) {
      if (r < 2)       v0 = W0[(16*t + row) * FEAT + 2*t + r];
      else if (r == 2) v0 = B0[16*t + row];
    }
    a0[r] = (_Float16)v0;

    float v1 = 0.f;
    if (row < 12)    v1 = W1[(12*t + row) * (16*NTOW) + 16*t + k];
    a1[r] = (_Float16)v1;

    float v2 = 0.f;
    if (row < 8 && k < 12) v2 = W2[(8*t + row) * (12*NTOW) + 12*t + k];
    a2[r] = (_Float16)v2;

    float v3 = 0.f;
    if (row == 0 && k < 8) v3 = W3[t * (8*NTOW) + 8*t + k];
    a3[r] = (_Float16)v3;
  }
  uint32_t* lrec = rec + 8 * l;
  h4_to_u2(a0, lrec + 0);
  h4_to_u2(a1, lrec + 2);
  h4_to_u2(a2, lrec + 4);
  h4_to_u2(a3, lrec + 6);

  if (l < 16) {
    // Interleaved bb layout: per kg-group {b1[4kg..4kg+3], b2[...]}.
    const float b1v = (l < 12) ? B1[12*t + l] : 0.f;
    const float b2v = (l < 8) ? B2[8*t + l] : 0.f;
    rec[OFF_BB + (l >> 2) * 8 +     (l & 3)] = __float_as_uint(b1v);
    rec[OFF_BB + (l >> 2) * 8 + 4 + (l & 3)] = __float_as_uint(b2v);
  }
  if (t == 0) {
    // Parallel b3+bias sum: 64 lanes load 2 each, wave shuffle-reduce.
    float s = B3[l] + B3[64 + l];
#pragma unroll
    for (int m = 32; m >= 1; m >>= 1) s += __shfl_xor(s, m);
    if (l == 0) pack[NTOW * REC] = __float_as_uint(s + bias[0]);
  }
}

// One block: tower group g (16 towers) x 256 samples (4 waves x 64).
// All 4 waves stream the SAME 16 tower records -> L1-resident weights.
// Grid caps occupancy at 4 waves/SIMD; waves_per_eu(4,4) tells the
// allocator so it may use the full 128-VGPR budget.
__global__ __launch_bounds__(256, 4)
__attribute__((amdgpu_waves_per_eu(4, 4)))
void bs_mfma(
    const float* __restrict__ x, const uint32_t* __restrict__ pack,
    float* __restrict__ out) {
  const int warp  = threadIdx.x >> 6;
  const int lane  = threadIdx.x & 63;
  const int col   = lane & 15;       // sample within tile
  const int kg    = lane >> 4;
  const int g     = blockIdx.x & 7;  // tower group: towers [16g, 16g+16)
  const int tile  = blockIdx.x >> 3;
  const int sbase = tile * 256 + warp * 64;

  const float cbias = __uint_as_float(pack[NTOW * REC]);

  // Per-lane x base: sample row (sbase+col), feature 2*(16g + kg).
  const float* __restrict__ xb =
      x + (size_t)(sbase + col) * FEAT + 2 * (g * 16 + kg);

  const uint32_t* __restrict__ fp = pack + (size_t)(g * 16) * REC + 8 * lane;
  const uint32_t* __restrict__ bp = pack + (size_t)(g * 16) * REC + OFF_BB + kg * 8;

  float acc0 = 0.f, acc1 = 0.f, acc2 = 0.f, acc3 = 0.f;

#pragma unroll 1
  for (int p = 0; p < 4; ++p) {      // packs of 4 towers — ROLLED
    // B0 fragments for this pack's 4 sample tiles (shared by the pack's
    // 4 towers). Named scalars -> guaranteed register allocation.
    const float* __restrict__ xp = xb + 8 * p;
    const h4_t bq0 = make_b0(xp + (size_t)0 * 16 * FEAT);
    const h4_t bq1 = make_b0(xp + (size_t)1 * 16 * FEAT);
    const h4_t bq2 = make_b0(xp + (size_t)2 * 16 * FEAT);
    const h4_t bq3 = make_b0(xp + (size_t)3 * 16 * FEAT);

    // Load all 4 towers' fragments (named; ~64 VGPR of weight state).
    const uint32_t* __restrict__ fpp = fp + (size_t)(4 * p) * REC;
    const uint32_t* __restrict__ bpp = bp + (size_t)(4 * p) * REC;
    const uint4  w01_0 = *(const uint4*)(fpp + 0 * REC);
    const uint4  w23_0 = *(const uint4*)(fpp + 0 * REC + 4);
    const uint4  w01_1 = *(const uint4*)(fpp + 1 * REC);
    const uint4  w23_1 = *(const uint4*)(fpp + 1 * REC + 4);
    const uint4  w01_2 = *(const uint4*)(fpp + 2 * REC);
    const uint4  w23_2 = *(const uint4*)(fpp + 2 * REC + 4);
    const uint4  w01_3 = *(const uint4*)(fpp + 3 * REC);
    const uint4  w23_3 = *(const uint4*)(fpp + 3 * REC + 4);
    const float4 bbA_0 = *(const float4*)(bpp + 0 * REC);
    const float4 bbB_0 = *(const float4*)(bpp + 0 * REC + 4);
    const float4 bbA_1 = *(const float4*)(bpp + 1 * REC);
    const float4 bbB_1 = *(const float4*)(bpp + 1 * REC + 4);
    const float4 bbA_2 = *(const float4*)(bpp + 2 * REC);
    const float4 bbB_2 = *(const float4*)(bpp + 2 * REC + 4);
    const float4 bbA_3 = *(const float4*)(bpp + 3 * REC);
    const float4 bbB_3 = *(const float4*)(bpp + 3 * REC + 4);

    const h4_t a0_0 = u2_to_h4(w01_0.x, w01_0.y), a1_0 = u2_to_h4(w01_0.z, w01_0.w);
    const h4_t a2_0 = u2_to_h4(w23_0.x, w23_0.y), a3_0 = u2_to_h4(w23_0.z, w23_0.w);
    const h4_t a0_1 = u2_to_h4(w01_1.x, w01_1.y), a1_1 = u2_to_h4(w01_1.z, w01_1.w);
    const h4_t a2_1 = u2_to_h4(w23_1.x, w23_1.y), a3_1 = u2_to_h4(w23_1.z, w23_1.w);
    const h4_t a0_2 = u2_to_h4(w01_2.x, w01_2.y), a1_2 = u2_to_h4(w01_2.z, w01_2.w);
    const h4_t a2_2 = u2_to_h4(w23_2.x, w23_2.y), a3_2 = u2_to_h4(w23_2.z, w23_2.w);
    const h4_t a0_3 = u2_to_h4(w01_3.x, w01_3.y), a1_3 = u2_to_h4(w01_3.z, w01_3.w);
    const h4_t a2_3 = u2_to_h4(w23_3.x, w23_3.y), a3_3 = u2_to_h4(w23_3.z, w23_3.w);
    const f4_t c1_0 = {bbA_0.x, bbA_0.y, bbA_0.z, bbA_0.w};
    const f4_t c2_0 = {bbB_0.x, bbB_0.y, bbB_0.z, bbB_0.w};
    const f4_t c1_1 = {bbA_1.x, bbA_1.y, bbA_1.z, bbA_1.w};
    const f4_t c2_1 = {bbB_1.x, bbB_1.y, bbB_1.z, bbB_1.w};
    const f4_t c1_2 = {bbA_2.x, bbA_2.y, bbA_2.z, bbA_2.w};
    const f4_t c2_2 = {bbB_2.x, bbB_2.y, bbB_2.z, bbB_2.w};
    const f4_t c1_3 = {bbA_3.x, bbA_3.y, bbA_3.z, bbA_3.w};
    const f4_t c2_3 = {bbB_3.x, bbB_3.y, bbB_3.z, bbB_3.w};

    const float2 r01 = oct_chain(a0_0, a1_0, a2_0, a3_0, c1_0, c2_0,
                                 a0_1, a1_1, a2_1, a3_1, c1_1, c2_1,
                                 a0_2, a1_2, a2_2, a3_2, c1_2, c2_2,
                                 a0_3, a1_3, a2_3, a3_3, c1_3, c2_3,
                                 bq0, bq1);
    acc0 += r01.x; acc1 += r01.y;
    const float2 r23 = oct_chain(a0_0, a1_0, a2_0, a3_0, c1_0, c2_0,
                                 a0_1, a1_1, a2_1, a3_1, c1_1, c2_1,
                                 a0_2, a1_2, a2_2, a3_2, c1_2, c2_2,
                                 a0_3, a1_3, a2_3, a3_3, c1_3, c2_3,
                                 bq2, bq3);
    acc2 += r23.x; acc3 += r23.y;
  }

  if (kg == 0) {
    const float add = (g == 0) ? cbias : 0.f;
    atomicAdd(out + sbase +  0 + col, acc0 + add);
    atomicAdd(out + sbase + 16 + col, acc1 + add);
    atomicAdd(out + sbase + 32 + col, acc2 + add);
    atomicAdd(out + sbase + 48 + col, acc3 + add);
  }
}

// ---- correctness-only fallback (ws too small; never expected) ----
__device__ __forceinline__ float gather_weight(
    int t, int i,
    const float* __restrict__ W0, const float* __restrict__ B0,
    const float* __restrict__ W1, const float* __restrict__ B1,
    const float* __restrict__ W2, const float* __restrict__ B2,
    const float* __restrict__ W3, const float* __restrict__ B3) {
  float v = 0.f;
  if (i < 32)       { int r = i >> 1, c = i & 1;               v = W0[(16*t + r)*FEAT + 2*t + c]; }
  else if (i < 48)  {                                           v = B0[16*t + (i - 32)]; }
  else if (i < 240) { int k = i - 48, r = k >> 4, c = k & 15;   v = W1[(12*t + r)*(16*NTOW) + 16*t + c]; }
  else if (i < 252) {                                           v = B1[12*t + (i - 240)]; }
  else if (i < 348) { int k = i - 252, r = k / 12, c = k - 12*r; v = W2[(8*t + r)*(12*NTOW) + 12*t + c]; }
  else if (i < 356) {                                           v = B2[8*t + (i - 348)]; }
  else if (i < 364) {                                           v = W3[t*(8*NTOW) + 8*t + (i - 356)]; }
  else if (i == 364){                                           v = B3[t]; }
  return v;
}

__global__ void bs_fwd_slow(
    const float* __restrict__ x,
    const float* __restrict__ W0, const float* __restrict__ B0,
    const float* __restrict__ W1, const float* __restrict__ B1,
    const float* __restrict__ W2, const float* __restrict__ B2,
    const float* __restrict__ W3, const float* __restrict__ B3,
    const float* __restrict__ bias,
    float* __restrict__ out) {
  const int s = blockIdx.x * blockDim.x + threadIdx.x;
  if (s >= BATCH) return;
  float acc = bias[0];
  for (int t = 0; t < NTOW; ++t) {
    float h0[16], h1[12], h2[8];
    const float x0 = x[(size_t)s*FEAT + 2*t], x1 = x[(size_t)s*FEAT + 2*t + 1];
    for (int r = 0; r < 16; ++r)
      h0[r] = fmaxf(0.f, gather_weight(t, 2*r, W0,B0,W1,B1,W2,B2,W3,B3) * x0
                        + gather_weight(t, 2*r+1, W0,B0,W1,B1,W2,B2,W3,B3) * x1
                        + gather_weight(t, 32+r, W0,B0,W1,B1,W2,B2,W3,B3));
    for (int r = 0; r < 12; ++r) {
      float sum = gather_weight(t, 240+r, W0,B0,W1,B1,W2,B2,W3,B3);
      for (int c = 0; c < 16; ++c)
        sum += gather_weight(t, 48+16*r+c, W0,B0,W1,B1,W2,B2,W3,B3) * h0[c];
      h1[r] = fmaxf(0.f, sum);
    }
    for (int r = 0; r < 8; ++r) {
      float sum = gather_weight(t, 348+r, W0,B0,W1,B1,W2,B2,W3,B3);
      for (int c = 0; c < 12; ++c)
        sum += gather_weight(t, 252+12*r+c, W0,B0,W1,B1,W2,B2,W3,B3) * h1[c];
      h2[r] = fmaxf(0.f, sum);
    }
    float sum = gather_weight(t, 364, W0,B0,W1,B1,W2,B2,W3,B3);
    for (int c = 0; c < 8; ++c)
      sum += gather_weight(t, 356+c, W0,B0,W1,B1,W2,B2,W3,B3) * h2[c];
    acc += sum;
  }
  out[s] = acc;
}

extern "C" void kernel_launch(void* const* d_in, const int* in_sizes, int n_in,
                              void* d_out, int out_size, void* d_ws, size_t ws_size,
                              hipStream_t stream) {
  const float* x    = (const float*)d_in[0];
  const float* W0   = (const float*)d_in[1];
  const float* B0   = (const float*)d_in[2];
  const float* W1   = (const float*)d_in[3];
  const float* B1   = (const float*)d_in[4];
  const float* W2   = (const float*)d_in[5];
  const float* B2   = (const float*)d_in[6];
  const float* W3   = (const float*)d_in[7];
  const float* B3   = (const float*)d_in[8];
  const float* bias = (const float*)d_in[9];
  float* out = (float*)d_out;

  const size_t packBytes = ((size_t)NTOW * REC + 1) * sizeof(uint32_t);

  if (ws_size >= packBytes) {
    uint32_t* pack = (uint32_t*)d_ws;
    // pack_frags also zeroes out[] (atomics accumulate; shape_loss stays 0).
    pack_frags<<<NTOW, 64, 0, stream>>>(W0, B0, W1, B1, W2, B2, W3, B3, bias, pack, out);
    const int blocks = (BATCH / 256) * 8;         // 1024 blocks
    bs_mfma<<<blocks, 256, 0, stream>>>(x, pack, out);
  } else {
    (void)hipMemsetAsync(d_out, 0, (size_t)out_size * sizeof(float), stream);
    bs_fwd_slow<<<BATCH / 256, 256, 0, stream>>>(x, W0, B0, W1, B1, W2, B2, W3, B3, bias, out);
  }
}